// Round 7
// baseline (141.873 us; speedup 1.0000x reference)
//
#include <hip/hip_runtime.h>
#include <math.h>

// VectorQuantizer via MFMA: in [32,64,64,64] fp32 NCHW (C=D=64), w [512,64] fp32.
// R6 post-mortem: vq_main 69us (both pipes <41%), ~70us in extra dispatches +
// fixed overhead. Wave-count-proportional costs dominate (each wave streams the
// whole 128KB B). R7: 4 A-tiles/wave (64 q), QB=256 -> half the waves; packed
// (dist|tile) keys in the fold (7 VALU/cand, truncation < tau covered by fp64
// re-rank); prep zeroes loss cell (memset dispatch dropped).
typedef short bf16x8 __attribute__((ext_vector_type(8)));
typedef float f32x4 __attribute__((ext_vector_type(4)));

#define VQ_D 64
#define VQ_K 512
#define VQ_NQ 131072
#define VQ_TOTAL 8388608
#define QB 256           // queries per block (4 waves x 4 A-tiles x 16)
#define NT 32            // B-tiles (512 / 16)
#define XPITCH 136       // ushorts per staged query row (272 B)

__device__ __forceinline__ ushort bf16_rne(float f) {
    uint u = __builtin_bit_cast(uint, f);
    u += 0x7fffu + ((u >> 16) & 1u);
    return (ushort)(u >> 16);
}
__device__ __forceinline__ float bf16_to_f(ushort h) {
    uint u = ((uint)h) << 16;
    return __builtin_bit_cast(float, u);
}

// ---- prep: w -> bf16 hi/lo in MFMA B-fragment order + fp32 norms + loss=0 ----
// wfrag layout (bf16x8 units): [tile t(32)][frag f(4: bh0,bh1,bl0,bl1)][lane(64)]
__global__ __launch_bounds__(128) void vq_prep(const float* __restrict__ w,
                                               ushort* __restrict__ wfrag,
                                               float* __restrict__ wn,
                                               float* __restrict__ out) {
    if (blockIdx.x == 0 && threadIdx.x == 0) out[VQ_TOTAL] = 0.f;
    const int k = blockIdx.x * 128 + threadIdx.x;   // one code per thread
    const float4* row = (const float4*)(w + k * VQ_D);
    const int t = k >> 4, col = k & 15;
    float nrm = 0.f;
    for (int g = 0; g < 8; ++g) {                   // granule g: d in [g*8, g*8+8)
        float4 a = row[2 * g], b4 = row[2 * g + 1];
        float v[8] = {a.x, a.y, a.z, a.w, b4.x, b4.y, b4.z, b4.w};
        ushort hi[8], lo[8];
#pragma unroll
        for (int j = 0; j < 8; ++j) {
            nrm = fmaf(v[j], v[j], nrm);
            hi[j] = bf16_rne(v[j]);
            lo[j] = bf16_rne(v[j] - bf16_to_f(hi[j]));
        }
        const int quad = g & 3, fh = g >> 2;
        const int lane = quad * 16 + col;
        bf16x8* basez = (bf16x8*)wfrag + t * 256 + lane;
        *(basez + fh * 64)       = *(bf16x8*)hi;    // bh{fh}
        *(basez + (2 + fh) * 64) = *(bf16x8*)lo;    // bl{fh}
    }
    wn[k] = nrm;
}

__global__ __launch_bounds__(256, 2) void vq_main(const float* __restrict__ in,
                                                  const float* __restrict__ w,
                                                  const ushort* __restrict__ wfrag,
                                                  const float* __restrict__ wng,
                                                  float* __restrict__ out) {
    __shared__ ushort x_lds[128 * XPITCH];  // 34 KB, reused for 2 staging phases
    __shared__ float wn_lds[VQ_K];          // 2 KB
    __shared__ float xn_lds[2][QB];         // partial query norms
    __shared__ float best_lds[QB], sec_lds[QB];
    __shared__ int   bi_lds[QB], si_lds[QB];

    const int tid  = threadIdx.x;
    const int lane = tid & 63;
    const int wid  = tid >> 6;          // wave wid owns queries wid*64 .. +63
    const int col  = lane & 15;
    const int quad = lane >> 4;
    const int n0  = blockIdx.x * QB;
    const int b   = n0 >> 12;
    const int hw0 = n0 & 4095;
    const float* xg = in + (b << 18) + hw0;

    wn_lds[tid]       = wng[tid];
    wn_lds[tid + 256] = wng[tid + 256];

    bf16x8 ah0[4], ah1[4], al0[4], al1[4];
    const int q_l = tid & 127, gh = tid >> 7;      // staging role
    const int arow_l = (wid & 1) * 64 + col;       // frag row within phase buffer

#pragma unroll
    for (int p = 0; p < 2; ++p) {
        // ---- stage queries [p*128, p*128+128) into x_lds ----
        {
            const float* xq = xg + p * 128 + q_l;
            float xnp = 0.f;
#pragma unroll
            for (int i = 0; i < 4; ++i) {
                const int g = gh * 4 + i;
                float v[8];
                ushort hi[8], lo[8];
#pragma unroll
                for (int j = 0; j < 8; ++j) v[j] = xq[(g * 8 + j) << 12];  // coalesced over q
#pragma unroll
                for (int j = 0; j < 8; ++j) {
                    xnp = fmaf(v[j], v[j], xnp);
                    hi[j] = bf16_rne(v[j]);
                    lo[j] = bf16_rne(v[j] - bf16_to_f(hi[j]));
                }
                *(bf16x8*)&x_lds[q_l * XPITCH + g * 8]      = *(bf16x8*)hi;
                *(bf16x8*)&x_lds[q_l * XPITCH + 64 + g * 8] = *(bf16x8*)lo;
            }
            xn_lds[gh][p * 128 + q_l] = xnp;
        }
        __syncthreads();
        // ---- waves whose queries are in this phase pull their A fragments ----
        if ((wid >> 1) == p) {
#pragma unroll
            for (int T = 0; T < 4; ++T) {
                const ushort* xr = x_lds + (arow_l + T * 16) * XPITCH;
                ah0[T] = *(const bf16x8*)(xr + quad * 8);
                ah1[T] = *(const bf16x8*)(xr + 32 + quad * 8);
                al0[T] = *(const bf16x8*)(xr + 64 + quad * 8);
                al1[T] = *(const bf16x8*)(xr + 96 + quad * 8);
            }
        }
        __syncthreads();
    }

    // ---- K-loop: B frags from global (L2-hot), packed (dist|tile) fold ----
    float best[16], secnd[16];
#pragma unroll
    for (int r = 0; r < 16; ++r) { best[r] = 3.0e38f; secnd[r] = 3.0e38f; }

    const bf16x8* wf = (const bf16x8*)wfrag + lane;
    bf16x8 bh0 = wf[0], bh1 = wf[64], bl0 = wf[128], bl1 = wf[192];

    for (int t = 0; t < NT; ++t) {
        bf16x8 nh0, nh1, nl0, nl1;
        if (t + 1 < NT) {
            const bf16x8* nx = wf + (t + 1) * 256;
            nh0 = nx[0]; nh1 = nx[64]; nl0 = nx[128]; nl1 = nx[192];
        }
        const float wnv = wn_lds[t * 16 + col];
#pragma unroll
        for (int T = 0; T < 4; ++T) {
            f32x4 accP = {0.f, 0.f, 0.f, 0.f}, accQ = {0.f, 0.f, 0.f, 0.f};
            accP = __builtin_amdgcn_mfma_f32_16x16x32_bf16(ah0[T], bh0, accP, 0, 0, 0);
            accP = __builtin_amdgcn_mfma_f32_16x16x32_bf16(ah1[T], bh1, accP, 0, 0, 0);
            accQ = __builtin_amdgcn_mfma_f32_16x16x32_bf16(ah0[T], bl0, accQ, 0, 0, 0);
            accQ = __builtin_amdgcn_mfma_f32_16x16x32_bf16(ah1[T], bl1, accQ, 0, 0, 0);
            accQ = __builtin_amdgcn_mfma_f32_16x16x32_bf16(al0[T], bh0, accQ, 0, 0, 0);
            accQ = __builtin_amdgcn_mfma_f32_16x16x32_bf16(al1[T], bh1, accQ, 0, 0, 0);
#pragma unroll
            for (int j = 0; j < 4; ++j) {          // C: row(query)=quad*4+j, col=code
                float dist = fmaf(-2.f, accP[j] + accQ[j], wnv);
                uint u = (__builtin_bit_cast(uint, dist) & 0xFFFFFFE0u) | (uint)t;
                float key = __builtin_bit_cast(float, u);
                const int r = T * 4 + j;
                float m = fmaxf(best[r], key);     // loser of (best, key)
                best[r]  = fminf(best[r], key);
                secnd[r] = fminf(secnd[r], m);
            }
        }
        bh0 = nh0; bh1 = nh1; bl0 = nl0; bl1 = nl1;
    }

    // ---- unpack keys -> (dist_class, global idx) ----
    float bD[16], sD[16];
    int bI[16], sI[16];
#pragma unroll
    for (int r = 0; r < 16; ++r) {
        uint ub = __builtin_bit_cast(uint, best[r]);
        uint us = __builtin_bit_cast(uint, secnd[r]);
        bI[r] = (int)(ub & 31u) * 16 + col;
        sI[r] = (int)(us & 31u) * 16 + col;
        bD[r] = __builtin_bit_cast(float, ub & 0xFFFFFFE0u);
        sD[r] = __builtin_bit_cast(float, us & 0xFFFFFFE0u);
    }

    // ---- merge across 16 col-lanes (disjoint code sets, lex (dist,idx)) ----
#pragma unroll
    for (int off = 1; off < 16; off <<= 1) {
#pragma unroll
        for (int r = 0; r < 16; ++r) {
            float ob = __shfl_xor(bD[r], off, 64);
            float os = __shfl_xor(sD[r], off, 64);
            int   oi = __shfl_xor(bI[r], off, 64);
            int   oc = __shfl_xor(sI[r], off, 64);
            bool oWins = (ob < bD[r]) || (ob == bD[r] && oi < bI[r]);
            float nb  = oWins ? ob    : bD[r];
            int   ni  = oWins ? oi    : bI[r];
            float c1  = oWins ? bD[r] : ob;      // loser's best
            int   ci1 = oWins ? bI[r] : oi;
            float c2  = oWins ? os    : sD[r];   // winner's second
            int   ci2 = oWins ? oc    : sI[r];
            bool c1w = (c1 < c2) || (c1 == c2 && ci1 < ci2);
            sD[r] = c1w ? c1  : c2;
            sI[r] = c1w ? ci1 : ci2;
            bD[r] = nb; bI[r] = ni;
        }
    }
    if (col == 0) {
#pragma unroll
        for (int r = 0; r < 16; ++r) {
            const int q = wid * 64 + (r >> 2) * 16 + quad * 4 + (r & 3);
            best_lds[q] = bD[r]; sec_lds[q] = sD[r];
            bi_lds[q] = bI[r];   si_lds[q] = sI[r];
        }
    }
    __syncthreads();

    // ---- epilogue: fp64 near-tie re-rank + loss (1 thread per query) ----
    {
        const int q = tid;
        float cb = best_lds[q], cs = sec_lds[q];
        int cbi = bi_lds[q], csi = si_lds[q];
        double chosen = (double)cb;
        if (cs - cb < 8e-3f) {
            const float* wb  = w + cbi * VQ_D;
            const float* ws2 = w + csi * VQ_D;
            const float* xqp = xg + q;
            double nb = 0.0, dotb = 0.0, ns = 0.0, dots = 0.0;
            for (int d = 0; d < VQ_D; ++d) {
                double xv = (double)xqp[d << 12];
                double wbv = (double)wb[d], wsv = (double)ws2[d];
                nb = fma(wbv, wbv, nb); dotb = fma(xv, wbv, dotb);
                ns = fma(wsv, wsv, ns); dots = fma(xv, wsv, dots);
            }
            double db = nb - 2.0 * dotb, ds = ns - 2.0 * dots;
            if (ds < db || (ds == db && csi < cbi)) { cbi = csi; chosen = ds; }
            else                                    { chosen = db; }
        }
        bi_lds[q] = cbi;
        double lq = (double)(xn_lds[0][q] + xn_lds[1][q]) + chosen;  // ||x-e||^2
#pragma unroll
        for (int off = 32; off > 0; off >>= 1)
            lq += __shfl_down(lq, off, 64);
        if ((tid & 63) == 0)
            atomicAdd(out + VQ_TOTAL, (float)(lq * (1.0 / (double)VQ_TOTAL)));
    }
    __syncthreads();

    // ---- quantized write: 1 thread/query, coalesced 256-float rows per d ----
    {
        const int q = tid;
        const float4* wrow = (const float4*)(w + bi_lds[q] * VQ_D);
        float* op = out + (b << 18) + hw0 + q;
#pragma unroll
        for (int i = 0; i < 16; ++i) {
            float4 v = wrow[i];
            op[(4 * i + 0) << 12] = v.x;
            op[(4 * i + 1) << 12] = v.y;
            op[(4 * i + 2) << 12] = v.z;
            op[(4 * i + 3) << 12] = v.w;
        }
    }
}

extern "C" void kernel_launch(void* const* d_in, const int* in_sizes, int n_in,
                              void* d_out, int out_size, void* d_ws, size_t ws_size,
                              hipStream_t stream) {
    const float* in = (const float*)d_in[0];
    const float* w  = (const float*)d_in[1];
    float* out = (float*)d_out;

    ushort* wfrag = (ushort*)d_ws;                    // 512*128 ushort = 128 KB
    float*  wn    = (float*)((char*)d_ws + 131072);   // 512 floats

    vq_prep<<<4, 128, 0, stream>>>(w, wfrag, wn, out);   // also zeroes loss cell
    vq_main<<<VQ_NQ / QB, 256, 0, stream>>>(in, w, wfrag, wn, out);
}

// Round 9
// 139.692 us; speedup vs baseline: 1.0156x; 1.0156x over previous
//
#include <hip/hip_runtime.h>
#include <math.h>

// VectorQuantizer via MFMA: in [32,64,64,64] fp32 NCHW (C=D=64), w [512,64] fp32.
// R8 failed (absmax 6.5) after changing 5 things at once. R9 = bisect:
// KEEP from R8: no x_lds, no K-loop barriers, A-frags direct from global,
//   grid 1024, B register prefetch.
// REVERT to R6/R7 (passed) verbatim: A = x (not -2x), acc=0 + dist =
//   fmaf(-2, accP+accQ, wnv), per-thread fp64 near-tie re-rank epilogue,
//   2-threads-per-query cooperative write, packed (dist|tile) key fold.
typedef short bf16x8 __attribute__((ext_vector_type(8)));
typedef float f32x4 __attribute__((ext_vector_type(4)));

#define VQ_D 64
#define VQ_K 512
#define VQ_NQ 131072
#define VQ_TOTAL 8388608
#define NT 32            // B tiles (512 / 16)
#define TAU 8e-3f

__device__ __forceinline__ ushort bf16_rne(float f) {
    uint u = __builtin_bit_cast(uint, f);
    u += 0x7fffu + ((u >> 16) & 1u);
    return (ushort)(u >> 16);
}
__device__ __forceinline__ float bf16_to_f(ushort h) {
    uint u = ((uint)h) << 16;
    return __builtin_bit_cast(float, u);
}

// ---- prep: w -> bf16 hi/lo in MFMA B-fragment order + fp32 norms + loss=0 ----
// (verbatim from R6/R7 -- passed)
__global__ __launch_bounds__(128) void vq_prep(const float* __restrict__ w,
                                               ushort* __restrict__ wfrag,
                                               float* __restrict__ wn,
                                               float* __restrict__ out) {
    if (blockIdx.x == 0 && threadIdx.x == 0) out[VQ_TOTAL] = 0.f;
    const int k = blockIdx.x * 128 + threadIdx.x;   // one code per thread
    const float4* row = (const float4*)(w + k * VQ_D);
    const int t = k >> 4, col = k & 15;
    float nrm = 0.f;
    for (int g = 0; g < 8; ++g) {                   // granule g: d in [g*8, g*8+8)
        float4 a = row[2 * g], b4 = row[2 * g + 1];
        float v[8] = {a.x, a.y, a.z, a.w, b4.x, b4.y, b4.z, b4.w};
        ushort hi[8], lo[8];
#pragma unroll
        for (int j = 0; j < 8; ++j) {
            nrm = fmaf(v[j], v[j], nrm);
            hi[j] = bf16_rne(v[j]);
            lo[j] = bf16_rne(v[j] - bf16_to_f(hi[j]));
        }
        const int quad = g & 3, fh = g >> 2;
        const int lane = quad * 16 + col;
        bf16x8* basez = (bf16x8*)wfrag + t * 256 + lane;
        *(basez + fh * 64)       = *(bf16x8*)hi;    // bh{fh}
        *(basez + (2 + fh) * 64) = *(bf16x8*)lo;    // bl{fh}
    }
    wn[k] = nrm;
}

__global__ __launch_bounds__(256, 3) void vq_main(const float* __restrict__ in,
                                                  const float* __restrict__ w,
                                                  const ushort* __restrict__ wfrag,
                                                  const float* __restrict__ wng,
                                                  float* __restrict__ out) {
    __shared__ float xn_lds[128];
    __shared__ float best_lds[128], sec_lds[128];
    __shared__ int   bi_lds[128], si_lds[128];

    const int tid  = threadIdx.x;
    const int lane = tid & 63;
    const int wid  = tid >> 6;
    const int col  = lane & 15;
    const int quad = lane >> 4;
    const int n0  = blockIdx.x * 128;          // block's 128 queries (one image)
    const int b   = n0 >> 12;
    const int hw0 = n0 & 4095;
    const float* xg0 = in + (b << 18) + hw0;
    const float* xgW = xg0 + wid * 32;         // this wave's 32 queries

    // ---- A fragments direct from global (x, bf16 hi/lo) + xnorm ----
    // A[m=col][k=quad*8+j]; same element mapping as R6/R7's x_lds path.
    bf16x8 ah0[2], ah1[2], al0[2], al1[2];
#pragma unroll
    for (int T = 0; T < 2; ++T) {
        const float* xq = xgW + T * 16 + col;  // query (wid*32 + T*16 + col)
        float sx = 0.f;
        ushort h0[8], l0[8], h1[8], l1[8];
#pragma unroll
        for (int j = 0; j < 8; ++j) {
            float v0 = xq[(quad * 8 + j) << 12];        // kstep0: d in [0,32)
            float v1 = xq[(32 + quad * 8 + j) << 12];   // kstep1: d in [32,64)
            sx = fmaf(v0, v0, sx);
            sx = fmaf(v1, v1, sx);
            h0[j] = bf16_rne(v0); l0[j] = bf16_rne(v0 - bf16_to_f(h0[j]));
            h1[j] = bf16_rne(v1); l1[j] = bf16_rne(v1 - bf16_to_f(h1[j]));
        }
        ah0[T] = *(bf16x8*)h0; al0[T] = *(bf16x8*)l0;
        ah1[T] = *(bf16x8*)h1; al1[T] = *(bf16x8*)l1;
        sx += __shfl_xor(sx, 16, 64);                   // sum the 4 quads
        sx += __shfl_xor(sx, 32, 64);
        if (quad == 0) xn_lds[wid * 32 + T * 16 + col] = sx;
    }

    // ---- K-loop (R7 math verbatim): acc=0, dist = fmaf(-2, dot, wn) ----
    float best[8], sec[8];
#pragma unroll
    for (int r = 0; r < 8; ++r) { best[r] = 3.0e38f; sec[r] = 3.0e38f; }

    const bf16x8* wf = (const bf16x8*)wfrag + lane;
    bf16x8 bh0 = wf[0], bh1 = wf[64], bl0 = wf[128], bl1 = wf[192];
    float wnv = wng[col];

#pragma unroll 1
    for (int t = 0; t < NT; ++t) {
        bf16x8 nh0, nh1, nl0, nl1;
        float wnn;
        if (t + 1 < NT) {
            const bf16x8* nx = wf + (t + 1) * 256;
            nh0 = nx[0]; nh1 = nx[64]; nl0 = nx[128]; nl1 = nx[192];
            wnn = wng[(t + 1) * 16 + col];
        }
#pragma unroll
        for (int T = 0; T < 2; ++T) {
            f32x4 accP = {0.f, 0.f, 0.f, 0.f}, accQ = {0.f, 0.f, 0.f, 0.f};
            accP = __builtin_amdgcn_mfma_f32_16x16x32_bf16(ah0[T], bh0, accP, 0, 0, 0);
            accP = __builtin_amdgcn_mfma_f32_16x16x32_bf16(ah1[T], bh1, accP, 0, 0, 0);
            accQ = __builtin_amdgcn_mfma_f32_16x16x32_bf16(ah0[T], bl0, accQ, 0, 0, 0);
            accQ = __builtin_amdgcn_mfma_f32_16x16x32_bf16(ah1[T], bl1, accQ, 0, 0, 0);
            accQ = __builtin_amdgcn_mfma_f32_16x16x32_bf16(al0[T], bh0, accQ, 0, 0, 0);
            accQ = __builtin_amdgcn_mfma_f32_16x16x32_bf16(al1[T], bh1, accQ, 0, 0, 0);
#pragma unroll
            for (int j = 0; j < 4; ++j) {          // C: row(query)=quad*4+j, col=code
                float dist = fmaf(-2.f, accP[j] + accQ[j], wnv);
                uint u = (__builtin_bit_cast(uint, dist) & 0xFFFFFFE0u) | (uint)t;
                float key = __builtin_bit_cast(float, u);
                const int r = T * 4 + j;
                float m = fmaxf(best[r], key);
                best[r] = fminf(best[r], key);
                sec[r]  = fminf(sec[r], m);
            }
        }
        bh0 = nh0; bh1 = nh1; bl0 = nl0; bl1 = nl1; wnv = wnn;
    }

    // ---- unpack packed keys -> (dist_class, global code idx) ----
    float bD[8], sD[8];
    int bI[8], sI[8];
#pragma unroll
    for (int r = 0; r < 8; ++r) {
        uint ub = __builtin_bit_cast(uint, best[r]);
        uint us = __builtin_bit_cast(uint, sec[r]);
        bI[r] = (int)(ub & 31u) * 16 + col;
        sI[r] = (int)(us & 31u) * 16 + col;
        bD[r] = __builtin_bit_cast(float, ub & 0xFFFFFFE0u);
        sD[r] = __builtin_bit_cast(float, us & 0xFFFFFFE0u);
    }

    // ---- merge across 16 col-lanes (R7 verbatim) ----
#pragma unroll
    for (int off = 1; off < 16; off <<= 1) {
#pragma unroll
        for (int r = 0; r < 8; ++r) {
            float ob = __shfl_xor(bD[r], off, 64);
            float os = __shfl_xor(sD[r], off, 64);
            int   oi = __shfl_xor(bI[r], off, 64);
            int   oc = __shfl_xor(sI[r], off, 64);
            bool oWins = (ob < bD[r]) || (ob == bD[r] && oi < bI[r]);
            float nb  = oWins ? ob    : bD[r];
            int   ni  = oWins ? oi    : bI[r];
            float c1  = oWins ? bD[r] : ob;      // loser's best
            int   ci1 = oWins ? bI[r] : oi;
            float c2  = oWins ? os    : sD[r];   // winner's second
            int   ci2 = oWins ? oc    : sI[r];
            bool c1w = (c1 < c2) || (c1 == c2 && ci1 < ci2);
            sD[r] = c1w ? c1  : c2;
            sI[r] = c1w ? ci1 : ci2;
            bD[r] = nb; bI[r] = ni;
        }
    }
    if (col == 0) {
#pragma unroll
        for (int r = 0; r < 8; ++r) {           // q in block = wid*32 + T*16 + quad*4 + j
            const int q = wid * 32 + (r >> 2) * 16 + quad * 4 + (r & 3);
            best_lds[q] = bD[r]; sec_lds[q] = sD[r];
            bi_lds[q] = bI[r];   si_lds[q] = sI[r];
        }
    }
    __syncthreads();

    // ---- epilogue (R6 verbatim): per-thread fp64 near-tie re-rank + loss ----
    if (tid < 128) {
        const int q = tid;
        float cb = best_lds[q], cs = sec_lds[q];
        int cbi = bi_lds[q], csi = si_lds[q];
        double chosen = (double)cb;
        if (cs - cb < TAU) {
            const float* wb  = w + cbi * VQ_D;
            const float* ws2 = w + csi * VQ_D;
            const float* xqp = xg0 + q;
            double nb = 0.0, dotb = 0.0, ns = 0.0, dots = 0.0;
            for (int d = 0; d < VQ_D; ++d) {
                double xv = (double)xqp[d << 12];
                double wbv = (double)wb[d], wsv = (double)ws2[d];
                nb = fma(wbv, wbv, nb); dotb = fma(xv, wbv, dotb);
                ns = fma(wsv, wsv, ns); dots = fma(xv, wsv, dots);
            }
            double db = nb - 2.0 * dotb, ds = ns - 2.0 * dots;
            if (ds < db || (ds == db && csi < cbi)) { cbi = csi; chosen = ds; }
            else                                    { chosen = db; }
        }
        bi_lds[q] = cbi;
        double lq = (double)xn_lds[q] + chosen;   // ||x-e||^2 = xnorm + (wn - 2 dot)
#pragma unroll
        for (int off = 32; off > 0; off >>= 1)
            lq += __shfl_down(lq, off, 64);
        if ((tid & 63) == 0)
            atomicAdd(out + VQ_TOTAL, (float)(lq * (1.0 / (double)VQ_TOTAL)));
    }
    __syncthreads();

    // ---- cooperative quantized write (R6 verbatim): 2 threads/query ----
    {
        const int q = tid & 127, half = tid >> 7;  // half covers d in [32*half, +32)
        const float4* wrow = (const float4*)(w + bi_lds[q] * VQ_D) + half * 8;
        float* op = out + (b << 18) + hw0 + q;
#pragma unroll
        for (int u = 0; u < 8; ++u) {
            float4 v = wrow[u];
            const int d = half * 32 + 4 * u;
            op[(d + 0) << 12] = v.x;
            op[(d + 1) << 12] = v.y;
            op[(d + 2) << 12] = v.z;
            op[(d + 3) << 12] = v.w;
        }
    }
}

extern "C" void kernel_launch(void* const* d_in, const int* in_sizes, int n_in,
                              void* d_out, int out_size, void* d_ws, size_t ws_size,
                              hipStream_t stream) {
    const float* in = (const float*)d_in[0];
    const float* w  = (const float*)d_in[1];
    float* out = (float*)d_out;

    ushort* wfrag = (ushort*)d_ws;                    // 512*128 ushort = 128 KB
    float*  wn    = (float*)((char*)d_ws + 131072);   // 512 floats

    vq_prep<<<4, 128, 0, stream>>>(w, wfrag, wn, out);   // also zeroes loss cell
    vq_main<<<VQ_NQ / 128, 256, 0, stream>>>(in, w, wfrag, wn, out);
}